// Round 2
// baseline (2352.015 us; speedup 1.0000x reference)
//
#include <hip/hip_runtime.h>
#include <math.h>
#include <stdint.h>

namespace {
constexpr int INN   = 512;
constexpr int HIDN  = 1024;
constexpr int LAY   = 2048;
constexpr int NITER = 512;
constexpr int NBLK  = 256;          // one block per CU
constexpr int TPB   = 256;          // 4 waves
constexpr int WVS   = TPB / 64;     // 4
constexpr int RPB   = LAY / NBLK;   // 8 rows per block
constexpr int RPW   = RPB / WVS;    // 2 rows per wave
constexpr int KPT   = LAY / 64;     // 32 k-chunks per lane
constexpr int EPT   = LAY / TPB;    // 8 tagged elements per thread
constexpr float EPS = 1e-12f;

__device__ __forceinline__ uint64_t pack(float v, uint32_t tag) {
  union { float f; uint32_t u; } c; c.f = v;
  return (uint64_t)c.u | ((uint64_t)tag << 32);
}
__device__ __forceinline__ float val_of(uint64_t p) {
  union { uint32_t u; float f; } c; c.u = (uint32_t)p; return c.f;
}

// Persistent kernel: all 512 iterations inside one launch.
// Activation exchange via tagged 8-byte words, agent-scope relaxed atomics
// (cross-XCD coherent, no fences, no L2 invalidation -> W stays cached/in regs).
__global__ __launch_bounds__(TPB) void bm_persistent(
    const float* __restrict__ x, const float* __restrict__ W,
    uint64_t* __restrict__ buf0, uint64_t* __restrict__ buf1,
    float* __restrict__ out) {
  __shared__ float s_act[LAY];
  __shared__ float s_red[WVS];
  const int tid = threadIdx.x;
  const int wv  = tid >> 6;
  const int ln  = tid & 63;
  const int blk = blockIdx.x;
  const int r0  = blk * RPB + wv * RPW;      // this wave's rows: r0, r0+1

  // ---- one-time: W rows into registers (64 VGPR/thread) ----
  float w0[KPT], w1[KPT];
  {
    const float* __restrict__ Wr0 = W + (size_t)r0 * LAY;
    const float* __restrict__ Wr1 = W + (size_t)(r0 + 1) * LAY;
#pragma unroll
    for (int i = 0; i < KPT; ++i) {
      w0[i] = Wr0[ln + 64 * i];
      w1[i] = Wr1[ln + 64 * i];
    }
  }
  const float x0 = (r0     < INN) ? x[r0]     : 0.0f;
  const float x1 = (r0 + 1 < INN) ? x[r0 + 1] : 0.0f;

  // ---- init act(t=0): visible = x, rest 0, tag 0, into buf0 ----
  if (tid < RPB) {
    const int r = blk * RPB + tid;
    const float v = (r < INN) ? x[r] : 0.0f;
    __hip_atomic_store(&buf0[r], pack(v, 0u),
                       __ATOMIC_RELAXED, __HIP_MEMORY_SCOPE_AGENT);
  }

  for (int t = 0; t <= NITER; ++t) {
    // ---- poll & stage act(t) from buf[t&1]; every element self-validates ----
    uint64_t* __restrict__ rb = (t & 1) ? buf1 : buf0;
    float myv[EPT];
    bool  done[EPT];
#pragma unroll
    for (int j = 0; j < EPT; ++j) done[j] = false;
    int rem = EPT;
    while (rem) {
#pragma unroll
      for (int j = 0; j < EPT; ++j) {
        if (!done[j]) {
          uint64_t p = __hip_atomic_load(&rb[tid + TPB * j],
                                         __ATOMIC_RELAXED, __HIP_MEMORY_SCOPE_AGENT);
          if ((uint32_t)(p >> 32) == (uint32_t)t) {
            done[j] = true; --rem;
            float v = val_of(p);
            myv[j] = v;
            s_act[tid + TPB * j] = v;
          }
        }
      }
    }

    // ---- sum of squares of hidden part (elements j>=4 are k>=1024) ----
    float ss = 0.0f;
#pragma unroll
    for (int j = EPT / 2; j < EPT; ++j) ss = fmaf(myv[j], myv[j], ss);
#pragma unroll
    for (int o = 1; o < 64; o <<= 1) ss += __shfl_xor(ss, o, 64);
    if (ln == 0) s_red[wv] = ss;
    __syncthreads();                    // also publishes s_act staging
    const float sst = s_red[0] + s_red[1] + s_red[2] + s_red[3];
    const float inv = 1.0f / fmaxf(sqrtf(sst), EPS);

    if (t == NITER) {
      // ---- final output: visible+y as-is, hidden normalized ----
#pragma unroll
      for (int j = 0; j < EPT; ++j) {
        const int k = tid + TPB * j;
        out[k] = (j < EPT / 2) ? myv[j] : myv[j] * inv;
      }
      return;
    }

    // ---- matvec: 2 rows/wave, W in registers, act from LDS ----
    float a0a = 0.f, a0b = 0.f, a1a = 0.f, a1b = 0.f;
#pragma unroll
    for (int i = 0; i < KPT / 2; ++i) {       // k in [0,1024)
      const float a = s_act[ln + 64 * i];
      a0a = fmaf(w0[i], a, a0a);
      a1a = fmaf(w1[i], a, a1a);
    }
#pragma unroll
    for (int i = KPT / 2; i < KPT; ++i) {     // k in [1024,2048): hidden
      const float a = s_act[ln + 64 * i];
      a0b = fmaf(w0[i], a, a0b);
      a1b = fmaf(w1[i], a, a1b);
    }
    float y0 = fmaf(inv, a0b, a0a);
    float y1 = fmaf(inv, a1b, a1a);
#pragma unroll
    for (int o = 1; o < 64; o <<= 1) {
      y0 += __shfl_xor(y0, o, 64);
      y1 += __shfl_xor(y1, o, 64);
    }
    __syncthreads();                    // WAR: s_act/s_red reads done before restage

    if (ln == 0) {
      float v0 = (r0     < INN) ? x0 : fmaxf(y0, 0.0f);
      float v1 = (r0 + 1 < INN) ? x1 : fmaxf(y1, 0.0f);
      uint64_t* __restrict__ wb = ((t + 1) & 1) ? buf1 : buf0;
      __hip_atomic_store(&wb[r0],     pack(v0, (uint32_t)(t + 1)),
                         __ATOMIC_RELAXED, __HIP_MEMORY_SCOPE_AGENT);
      __hip_atomic_store(&wb[r0 + 1], pack(v1, (uint32_t)(t + 1)),
                         __ATOMIC_RELAXED, __HIP_MEMORY_SCOPE_AGENT);
    }
  }
}
} // namespace

extern "C" void kernel_launch(void* const* d_in, const int* in_sizes, int n_in,
                              void* d_out, int out_size, void* d_ws, size_t ws_size,
                              hipStream_t stream) {
  const float* x = (const float*)d_in[0];
  // d_in[1] (y) only used as zeros in the reference.
  const float* W = (const float*)d_in[2];
  float* out = (float*)d_out;

  uint64_t* buf0 = (uint64_t*)d_ws;
  uint64_t* buf1 = buf0 + LAY;

  // Invalidate all stale tags (0xFF -> tag 0xFFFFFFFF, never matches 0..512).
  // Required both for the fresh-alloc first call and between graph replays.
  hipMemsetAsync(d_ws, 0xFF, (size_t)2 * LAY * sizeof(uint64_t), stream);

  bm_persistent<<<dim3(NBLK), dim3(TPB), 0, stream>>>(x, W, buf0, buf1, out);
}

// Round 4
// 1918.643 us; speedup vs baseline: 1.2259x; 1.2259x over previous
//
#include <hip/hip_runtime.h>
#include <math.h>
#include <stdint.h>

namespace {
constexpr int INN   = 512;          // visible input rows (act[:512] == x always)
constexpr int LAY   = 2048;
constexpr int DYN   = LAY - INN;    // 1536 dynamic elements: act[512..2048)
constexpr int NITER = 512;
constexpr int NBLK  = 192;          // 1536 rows / 8 rows per block
constexpr int TPB   = 256;          // 4 waves
constexpr int WVS   = TPB / 64;     // 4
constexpr int RPW   = 2;            // rows per wave
constexpr int KC    = DYN / 64;     // 24 k-chunks per lane (dynamic columns)
constexpr int KX    = INN / 64;     // 8 k-chunks (x columns, precomputed)
constexpr int EPT   = DYN / TPB;    // 6 tagged elements polled per thread
constexpr float EPS = 1e-12f;

__device__ __forceinline__ uint64_t pack(float v, uint32_t tag) {
  union { float f; uint32_t u; } c; c.f = v;
  return (uint64_t)c.u | ((uint64_t)tag << 32);
}
__device__ __forceinline__ float val_of(uint64_t p) {
  union { uint32_t u; float f; } c; c.u = (uint32_t)p; return c.f;
}
__device__ __forceinline__ void tag_store(uint64_t* p, uint64_t v) {
  __hip_atomic_store(p, v, __ATOMIC_RELAXED, __HIP_MEMORY_SCOPE_AGENT);
}
__device__ __forceinline__ uint64_t tag_load(const uint64_t* p) {
  return __hip_atomic_load(p, __ATOMIC_RELAXED, __HIP_MEMORY_SCOPE_AGENT);
}

// Persistent kernel, 512 iterations in one launch.
// act[:512]==x always -> rows <512 never computed/communicated; their column
// contribution is a per-row constant c_r = W[r,:512]@x (reduced ONCE at
// startup; added AFTER the per-iteration lane reduction — round-2 bug was
// adding it before, counting it 64x). Hidden part stored UN-normalized;
// inv_norm recomputed per block and folded into the matvec.
// Exchange: tagged (value,iter) 8-byte words, relaxed agent-scope atomics.
// Invariant (overwrite safety): a block stores tag t+1 only after block-wide
// consumption of tag t (__syncthreads between poll and store), so tag t+2
// stores (which clobber tag t) can only happen after every block consumed t.
__global__ __launch_bounds__(TPB) void bm_persistent(
    const float* __restrict__ x, const float* __restrict__ W,
    uint64_t* __restrict__ buf0, uint64_t* __restrict__ buf1,
    float* __restrict__ out) {
  __shared__ float s_act[DYN];
  __shared__ float s_red[WVS];
  const int tid = threadIdx.x;
  const int wv  = tid >> 6;
  const int ln  = tid & 63;
  const int blk = blockIdx.x;
  const int r0  = INN + blk * (WVS * RPW) + wv * RPW;   // this wave's rows (>=512)

  // ---- one-time: W[r, 512:2048] into registers (48 VGPR/thread) ----
  float w0[KC], w1[KC];
  const float* __restrict__ Wr0 = W + (size_t)r0 * LAY;
  const float* __restrict__ Wr1 = Wr0 + LAY;
#pragma unroll
  for (int i = 0; i < KC; ++i) {
    w0[i] = Wr0[INN + ln + 64 * i];
    w1[i] = Wr1[INN + ln + 64 * i];
  }
  // ---- one-time: c_r = W[r,:512] @ x  (fully reduced; all lanes hold sum) ----
  float c0 = 0.f, c1 = 0.f;
#pragma unroll
  for (int i = 0; i < KX; ++i) {
    const float xv = x[ln + 64 * i];
    c0 = fmaf(Wr0[ln + 64 * i], xv, c0);
    c1 = fmaf(Wr1[ln + 64 * i], xv, c1);
  }
#pragma unroll
  for (int o = 1; o < 64; o <<= 1) {
    c0 += __shfl_xor(c0, o, 64);
    c1 += __shfl_xor(c1, o, 64);
  }

  // ---- bootstrap: act(1) = relu(c_r) (h(0)=0, y(0)=0), tag 1 -> buf1 ----
  if (ln == 0) {
    tag_store(&buf1[r0 - INN],     pack(fmaxf(c0, 0.f), 1u));
    tag_store(&buf1[r0 - INN + 1], pack(fmaxf(c1, 0.f), 1u));
  }

  float myv[EPT];
  float inv = 0.f;
  for (int t = 1;; ++t) {
    if (t == NITER && blk != 0) return;   // non-0 blocks already stored tag 512
    uint64_t* __restrict__ rb = (t & 1) ? buf1 : buf0;

    // ---- poll act(t): BATCHED reload of all 6 elements per pass ----
    uint64_t pv[EPT];
    for (;;) {
      bool ok = true;
#pragma unroll
      for (int j = 0; j < EPT; ++j)
        pv[j] = tag_load(&rb[tid + TPB * j]);
#pragma unroll
      for (int j = 0; j < EPT; ++j)
        ok &= ((uint32_t)(pv[j] >> 32) == (uint32_t)t);
      if (ok) break;
    }

    // ---- stage to LDS + sum-of-squares of hidden part (j>=2 <=> k>=1024) ----
    float ss = 0.f;
#pragma unroll
    for (int j = 0; j < EPT; ++j) {
      const float v = val_of(pv[j]);
      myv[j] = v;
      s_act[tid + TPB * j] = v;
      if (j >= 2) ss = fmaf(v, v, ss);
    }
#pragma unroll
    for (int o = 1; o < 64; o <<= 1) ss += __shfl_xor(ss, o, 64);
    if (ln == 0) s_red[wv] = ss;
    __syncthreads();                        // poll done block-wide; s_act/s_red ready
    inv = 1.0f / fmaxf(sqrtf(s_red[0] + s_red[1] + s_red[2] + s_red[3]), EPS);

    if (t == NITER) break;                  // blk 0 falls through to output

    // ---- matvec: y_r = c_r + W[r,512:1024]@a_y + inv * W[r,1024:2048]@h ----
    float a0 = 0.f, b0 = 0.f, a1 = 0.f, b1 = 0.f;
#pragma unroll
    for (int i = 0; i < 8; ++i) {           // p in [0,512): y-region
      const float a = s_act[ln + 64 * i];
      a0 = fmaf(w0[i], a, a0);
      a1 = fmaf(w1[i], a, a1);
    }
#pragma unroll
    for (int i = 8; i < KC; ++i) {          // p in [512,1536): hidden region
      const float a = s_act[ln + 64 * i];
      b0 = fmaf(w0[i], a, b0);
      b1 = fmaf(w1[i], a, b1);
    }
    // reduce per-lane partials FIRST; add fully-reduced c_r AFTER (fix).
    float y0 = fmaf(inv, b0, a0);
    float y1 = fmaf(inv, b1, a1);
#pragma unroll
    for (int o = 1; o < 64; o <<= 1) {
      y0 += __shfl_xor(y0, o, 64);
      y1 += __shfl_xor(y1, o, 64);
    }
    y0 += c0;
    y1 += c1;
    __syncthreads();                        // WAR: LDS reads done before next stage

    if (ln == 0) {
      uint64_t* __restrict__ wb = ((t + 1) & 1) ? buf1 : buf0;
      tag_store(&wb[r0 - INN],     pack(fmaxf(y0, 0.f), (uint32_t)(t + 1)));
      tag_store(&wb[r0 - INN + 1], pack(fmaxf(y1, 0.f), (uint32_t)(t + 1)));
    }
  }

  // ---- blk 0: write final output ----
  out[tid]       = x[tid];
  out[tid + TPB] = x[tid + TPB];
#pragma unroll
  for (int j = 0; j < EPT; ++j)
    out[INN + tid + TPB * j] = (j < 2) ? myv[j] : myv[j] * inv;
}
} // namespace

extern "C" void kernel_launch(void* const* d_in, const int* in_sizes, int n_in,
                              void* d_out, int out_size, void* d_ws, size_t ws_size,
                              hipStream_t stream) {
  const float* x = (const float*)d_in[0];
  // d_in[1] (y) only enters the reference as zeros_like -> unused.
  const float* W = (const float*)d_in[2];
  float* out = (float*)d_out;

  uint64_t* buf0 = (uint64_t*)d_ws;
  uint64_t* buf1 = buf0 + DYN;

  // Invalidate stale tags (0xFFFFFFFF matches no t in 1..512) — needed on the
  // first call and between graph replays (harness does not re-poison d_ws).
  hipMemsetAsync(d_ws, 0xFF, (size_t)2 * DYN * sizeof(uint64_t), stream);

  bm_persistent<<<dim3(NBLK), dim3(TPB), 0, stream>>>(x, W, buf0, buf1, out);
}

// Round 5
// 1826.329 us; speedup vs baseline: 1.2878x; 1.0505x over previous
//
#include <hip/hip_runtime.h>
#include <math.h>
#include <stdint.h>

namespace {
constexpr int INN   = 512;          // visible input rows (act[:512] == x always)
constexpr int LAY   = 2048;
constexpr int DYN   = LAY - INN;    // 1536 dynamic elements: act[512..2048)
constexpr int NITER = 512;
constexpr int NBLK  = 64;           // FEWER, FATTER blocks: cut poll contention 3x
constexpr int TPB   = 256;          // 4 waves
constexpr int WVS   = TPB / 64;     // 4
constexpr int RPW   = 6;            // rows per wave
constexpr int RPB   = WVS * RPW;    // 24 rows per block; 64*24 = 1536 ✓
constexpr int KC    = DYN / 64;     // 24 k-chunks per lane (dynamic columns)
constexpr int KX    = INN / 64;     // 8 k-chunks (x columns, precomputed)
constexpr int EPT   = DYN / TPB;    // 6 tagged elements polled per thread
constexpr float EPS = 1e-12f;

__device__ __forceinline__ uint64_t pack(float v, uint32_t tag) {
  union { float f; uint32_t u; } c; c.f = v;
  return (uint64_t)c.u | ((uint64_t)tag << 32);
}
__device__ __forceinline__ float val_of(uint64_t p) {
  union { uint32_t u; float f; } c; c.u = (uint32_t)p; return c.f;
}
__device__ __forceinline__ void tag_store(uint64_t* p, uint64_t v) {
  __hip_atomic_store(p, v, __ATOMIC_RELAXED, __HIP_MEMORY_SCOPE_AGENT);
}
__device__ __forceinline__ uint64_t tag_load(const uint64_t* p) {
  return __hip_atomic_load(p, __ATOMIC_RELAXED, __HIP_MEMORY_SCOPE_AGENT);
}

// Persistent kernel, 512 iterations in one launch. Same validated scheme as
// round 3 (tagged 8-byte exchange, relaxed agent-scope atomics; c_r added
// AFTER the lane reduction); only the geometry changed: 64 blocks x 24 rows
// (6 rows/wave, W rows in 144 VGPRs) to cut MALL poll contention 3x.
// Invariant (overwrite safety): a block stores tag t+1 only after block-wide
// consumption of tag t (__syncthreads between poll and store), so tag t+2
// stores (which clobber tag t) can only happen after every block consumed t.
__global__ __launch_bounds__(TPB) void bm_persistent(
    const float* __restrict__ x, const float* __restrict__ W,
    uint64_t* __restrict__ buf0, uint64_t* __restrict__ buf1,
    float* __restrict__ out) {
  __shared__ float s_act[DYN];
  __shared__ float s_red[WVS];
  const int tid = threadIdx.x;
  const int wv  = tid >> 6;
  const int ln  = tid & 63;
  const int blk = blockIdx.x;
  const int r0  = INN + blk * RPB + wv * RPW;   // this wave's 6 rows (>=512)

  // ---- one-time: W[r, 512:2048] into registers (6 x 24 = 144 VGPR) ----
  float w[RPW][KC];
  const float* __restrict__ Wr = W + (size_t)r0 * LAY;
#pragma unroll
  for (int r = 0; r < RPW; ++r)
#pragma unroll
    for (int i = 0; i < KC; ++i)
      w[r][i] = Wr[(size_t)r * LAY + INN + ln + 64 * i];

  // ---- one-time: c_r = W[r,:512] @ x  (fully reduced; all lanes hold sum) ----
  float xv[KX];
#pragma unroll
  for (int i = 0; i < KX; ++i) xv[i] = x[ln + 64 * i];
  float c[RPW];
#pragma unroll
  for (int r = 0; r < RPW; ++r) {
    float cc = 0.f;
#pragma unroll
    for (int i = 0; i < KX; ++i)
      cc = fmaf(Wr[(size_t)r * LAY + ln + 64 * i], xv[i], cc);
#pragma unroll
    for (int o = 1; o < 64; o <<= 1) cc += __shfl_xor(cc, o, 64);
    c[r] = cc;
  }

  // ---- bootstrap: act(1) = relu(c_r) (h(0)=0, y(0)=0), tag 1 -> buf1 ----
  if (ln == 0) {
#pragma unroll
    for (int r = 0; r < RPW; ++r)
      tag_store(&buf1[r0 - INN + r], pack(fmaxf(c[r], 0.f), 1u));
  }

  float myv[EPT];
  float inv = 0.f;
  for (int t = 1;; ++t) {
    if (t == NITER && blk != 0) return;   // non-0 blocks already stored tag 512
    uint64_t* __restrict__ rb = (t & 1) ? buf1 : buf0;

    // ---- poll act(t): batched reload of all 6 elements per pass ----
    uint64_t pv[EPT];
    for (;;) {
      bool ok = true;
#pragma unroll
      for (int j = 0; j < EPT; ++j)
        pv[j] = tag_load(&rb[tid + TPB * j]);
#pragma unroll
      for (int j = 0; j < EPT; ++j)
        ok &= ((uint32_t)(pv[j] >> 32) == (uint32_t)t);
      if (ok) break;
    }

    // ---- stage to LDS + sum-of-squares of hidden part (j>=2 <=> k>=1024) ----
    float ss = 0.f;
#pragma unroll
    for (int j = 0; j < EPT; ++j) {
      const float v = val_of(pv[j]);
      myv[j] = v;
      s_act[tid + TPB * j] = v;
      if (j >= 2) ss = fmaf(v, v, ss);
    }
#pragma unroll
    for (int o = 1; o < 64; o <<= 1) ss += __shfl_xor(ss, o, 64);
    if (ln == 0) s_red[wv] = ss;
    __syncthreads();                        // poll done block-wide; s_act/s_red ready
    inv = 1.0f / fmaxf(sqrtf(s_red[0] + s_red[1] + s_red[2] + s_red[3]), EPS);

    if (t == NITER) break;                  // blk 0 falls through to output

    // ---- matvec: y_r = c_r + W[r,512:1024]@a_y + inv * W[r,1024:2048]@h ----
    float aa[RPW], bb[RPW];
#pragma unroll
    for (int r = 0; r < RPW; ++r) { aa[r] = 0.f; bb[r] = 0.f; }
#pragma unroll
    for (int i = 0; i < 8; ++i) {           // p in [0,512): y-region
      const float a = s_act[ln + 64 * i];
#pragma unroll
      for (int r = 0; r < RPW; ++r) aa[r] = fmaf(w[r][i], a, aa[r]);
    }
#pragma unroll
    for (int i = 8; i < KC; ++i) {          // p in [512,1536): hidden region
      const float a = s_act[ln + 64 * i];
#pragma unroll
      for (int r = 0; r < RPW; ++r) bb[r] = fmaf(w[r][i], a, bb[r]);
    }
    // reduce per-lane partials FIRST; add fully-reduced c_r AFTER.
    float y[RPW];
#pragma unroll
    for (int r = 0; r < RPW; ++r) y[r] = fmaf(inv, bb[r], aa[r]);
#pragma unroll
    for (int o = 1; o < 64; o <<= 1) {
#pragma unroll
      for (int r = 0; r < RPW; ++r) y[r] += __shfl_xor(y[r], o, 64);
    }
#pragma unroll
    for (int r = 0; r < RPW; ++r) y[r] += c[r];
    __syncthreads();                        // WAR: LDS reads done before next stage

    if (ln == 0) {
      uint64_t* __restrict__ wb = ((t + 1) & 1) ? buf1 : buf0;
#pragma unroll
      for (int r = 0; r < RPW; ++r)
        tag_store(&wb[r0 - INN + r], pack(fmaxf(y[r], 0.f), (uint32_t)(t + 1)));
    }
  }

  // ---- blk 0: write final output ----
  out[tid]       = x[tid];
  out[tid + TPB] = x[tid + TPB];
#pragma unroll
  for (int j = 0; j < EPT; ++j)
    out[INN + tid + TPB * j] = (j < 2) ? myv[j] : myv[j] * inv;
}
} // namespace

extern "C" void kernel_launch(void* const* d_in, const int* in_sizes, int n_in,
                              void* d_out, int out_size, void* d_ws, size_t ws_size,
                              hipStream_t stream) {
  const float* x = (const float*)d_in[0];
  // d_in[1] (y) only enters the reference as zeros_like -> unused.
  const float* W = (const float*)d_in[2];
  float* out = (float*)d_out;

  uint64_t* buf0 = (uint64_t*)d_ws;
  uint64_t* buf1 = buf0 + DYN;

  // Invalidate stale tags (0xFFFFFFFF matches no t in 1..512) — needed on the
  // first call and between graph replays (harness does not re-poison d_ws).
  hipMemsetAsync(d_ws, 0xFF, (size_t)2 * DYN * sizeof(uint64_t), stream);

  bm_persistent<<<dim3(NBLK), dim3(TPB), 0, stream>>>(x, W, buf0, buf1, out);
}